// Round 7
// baseline (881.504 us; speedup 1.0000x reference)
//
#include <hip/hip_runtime.h>
#include <stdint.h>

#define NPTS 8192
#define NB 4
#define KNN 16

typedef unsigned long long u64;
typedef unsigned int u32;

// monotone float -> uint32 transform (ascending float order == ascending uint order)
__device__ __forceinline__ u32 f2ord(float f) {
    u32 b = __float_as_uint(f);
    return (b & 0x80000000u) ? ~b : (b | 0x80000000u);
}
__device__ __forceinline__ float ord2f(u32 u) {
    u32 b = (u & 0x80000000u) ? (u & 0x7fffffffu) : ~u;
    return __uint_as_float(b);
}
__device__ __forceinline__ u64 shflx64(u64 v, int m) {
    u32 lo = (u32)v, hi = (u32)(v >> 32);
    lo = __shfl_xor(lo, m, 64);
    hi = __shfl_xor(hi, m, 64);
    return ((u64)hi << 32) | lo;
}

// Pack (x, y, z, ||x||^2) per point. sq via mul-add chain (np.sum(p*p)):
// ((x*x + y*y) + z*z), all _rn (one IEEE rounding per op, no contraction).
__global__ __launch_bounds__(256) void pack_kernel(const float* __restrict__ pos,
                                                   float4* __restrict__ pos4) {
    int t = blockIdx.x * 256 + threadIdx.x;          // 0..32767, grid sized exactly
    int b = t >> 13;
    int j = t & (NPTS - 1);
    const float* p = pos + (size_t)b * 3 * NPTS;
    float x = p[j];
    float y = p[NPTS + j];
    float z = p[2 * NPTS + j];
    float sq = __fadd_rn(__fadd_rn(__fmul_rn(x, x), __fmul_rn(y, y)), __fmul_rn(z, z));
    pos4[t] = make_float4(x, y, z, sq);
}

// One wave per query row. Each lane scans 128 candidates, keeps a sorted
// top-16 (u64 keys) in registers; a wave-shared threshold T (min over lanes
// of each lane's 16th-smallest) exactly prunes candidates that cannot be in
// the global top-16. Final merge: 16 rounds of wave-wide min tournament.
__global__ __launch_bounds__(256) void knn_kernel(const float4* __restrict__ pos4,
                                                  float* __restrict__ out) {
    const int lane = threadIdx.x & 63;
    const int row = blockIdx.x * 4 + (threadIdx.x >> 6);   // 0..32767
    const int b = row >> 13;
    const int i = row & (NPTS - 1);

    const float4* __restrict__ P = pos4 + (size_t)b * NPTS;
    const float4 q = P[i];   // wave-uniform broadcast load

    u64 kk[KNN];
#pragma unroll
    for (int t = 0; t < KNN; ++t) kk[t] = ~0ULL;

    for (int cc = 0; cc < 8; ++cc) {
        // refresh shared threshold: wave-min of lanes' current 16th-smallest.
        // Each lane's kk[15] >= final global 16th-smallest (any key rejected
        // via key > T has >=16 distinct smaller keys), so pruning is exact.
        u64 T = kk[KNN - 1];
#pragma unroll
        for (int s = 1; s < 64; s <<= 1) {
            u64 o = shflx64(T, s);
            T = o < T ? o : T;
        }
#pragma unroll 4
        for (int c = 0; c < 16; ++c) {
            int j = (cc * 16 + c) * 64 + lane;
            float4 p = P[j];
            // BLAS-sgemm-style dot (k=3 fma microkernel accumulation):
            //   dot = fma(z,z', fma(y,y', round(x*x')))
            // combine: d2 = (sq_i + sq_j) - (2*dot), one rounding per op.
            float dot = __fmaf_rn(q.z, p.z, __fmaf_rn(q.y, p.y, __fmul_rn(q.x, p.x)));
            float d2 = __fsub_rn(__fadd_rn(q.w, p.w), __fmul_rn(2.0f, dot));
            u64 key = ((u64)f2ord(d2) << 13) | (u32)j;   // (d2 asc, idx asc)
            if (key < T && key < kk[KNN - 1]) {
                // sorted bubble insert (all indices compile-time constant)
                u64 nk = key;
#pragma unroll
                for (int t = 0; t < KNN; ++t) {
                    u64 lo = kk[t] < nk ? kk[t] : nk;
                    nk = kk[t] ^ nk ^ lo;   // the larger one
                    kk[t] = lo;
                }
            }
        }
    }

    // tournament merge: keys are globally unique (j embedded), so the
    // winner is popped from exactly one lane's list each round.
    u32 myidx = 0;
    float myd2 = 0.0f;
#pragma unroll 1
    for (int r = 0; r < KNN; ++r) {
        u64 m = kk[0];
#pragma unroll
        for (int s = 1; s < 64; s <<= 1) {
            u64 o = shflx64(m, s);
            m = o < m ? o : m;
        }
        if (kk[0] == m) {
#pragma unroll
            for (int t = 0; t < KNN - 1; ++t) kk[t] = kk[t + 1];
            kk[KNN - 1] = ~0ULL;
        }
        if (lane == r) {
            myidx = (u32)(m & (NPTS - 1));
            myd2 = ord2f((u32)(m >> 13));
        }
    }

    if (lane < KNN) {
        // outputs: NN [B,K,N] then distances [B,K,N], both as float32
        size_t o1 = (size_t)(b * KNN + lane) * NPTS + i;
        out[o1] = (float)myidx;
        out[(size_t)NB * KNN * NPTS + o1] = myd2;
    }
}

extern "C" void kernel_launch(void* const* d_in, const int* in_sizes, int n_in,
                              void* d_out, int out_size, void* d_ws, size_t ws_size,
                              hipStream_t stream) {
    const float* pos = (const float*)d_in[0];
    float* out = (float*)d_out;
    float4* pos4 = (float4*)d_ws;   // 4*8192*16 B = 512 KB scratch

    pack_kernel<<<dim3(NB * NPTS / 256), dim3(256), 0, stream>>>(pos, pos4);
    knn_kernel<<<dim3(NB * NPTS / 4), dim3(256), 0, stream>>>(pos4, out);
}

// Round 8
// 711.315 us; speedup vs baseline: 1.2393x; 1.2393x over previous
//
#include <hip/hip_runtime.h>
#include <stdint.h>

#define NPTS 8192
#define NB 4
#define KNN 16

typedef unsigned long long u64;
typedef unsigned int u32;

// monotone float -> uint32 transform (ascending float order == ascending uint order)
__device__ __forceinline__ u32 f2ord(float f) {
    u32 b = __float_as_uint(f);
    return (b & 0x80000000u) ? ~b : (b | 0x80000000u);
}
__device__ __forceinline__ float ord2f(u32 u) {
    u32 b = (u & 0x80000000u) ? (u & 0x7fffffffu) : ~u;
    return __uint_as_float(b);
}
__device__ __forceinline__ u64 shflx64(u64 v, int m) {
    u32 lo = (u32)v, hi = (u32)(v >> 32);
    lo = __shfl_xor(lo, m, 64);
    hi = __shfl_xor(hi, m, 64);
    return ((u64)hi << 32) | lo;
}

// Pack (x, y, z, ||x||^2) per point. sq via mul-add chain (np.sum(p*p)):
// ((x*x + y*y) + z*z), all _rn (one IEEE rounding per op, no contraction).
__global__ __launch_bounds__(256) void pack_kernel(const float* __restrict__ pos,
                                                   float4* __restrict__ pos4) {
    int t = blockIdx.x * 256 + threadIdx.x;          // 0..32767, grid sized exactly
    int b = t >> 13;
    int j = t & (NPTS - 1);
    const float* p = pos + (size_t)b * 3 * NPTS;
    float x = p[j];
    float y = p[NPTS + j];
    float z = p[2 * NPTS + j];
    float sq = __fadd_rn(__fadd_rn(__fmul_rn(x, x), __fmul_rn(y, y)), __fmul_rn(z, z));
    pos4[t] = make_float4(x, y, z, sq);
}

// One wave per query row. Scan keeps per-lane sorted top-16 as RAW f32 d2
// (+ parallel idx regs): f32 compares are ordering-exact; within-lane ties
// stay index-ordered because stream order == index order and inserts use
// strict <. Cross-lane ties are settled at the final tournament via u64
// (f2ord(d2)<<13)|idx keys. Wave-shared prune T = wave-min of lanes' 16th
// (reject d2 > T is exact: T-lane holds 16 strictly-smaller entries).
__global__ __launch_bounds__(256) void knn_kernel(const float4* __restrict__ pos4,
                                                  float* __restrict__ out) {
    const int lane = threadIdx.x & 63;
    const int row = blockIdx.x * 4 + (threadIdx.x >> 6);   // 0..32767
    const int b = row >> 13;
    const int i = row & (NPTS - 1);

    const float4* __restrict__ P = pos4 + (size_t)b * NPTS;
    const float4 q = P[i];   // wave-uniform broadcast load

    float ko[KNN];   // sorted ascending (d2, then stream/index order on ties)
    u32 ki[KNN];

    // ---- warm-up: first 16 candidates (cc=0), triangular static insert ----
#pragma unroll
    for (int c = 0; c < KNN; ++c) {
        int j = c * 64 + lane;
        float4 p = P[j];
        float dot = __fmaf_rn(q.z, p.z, __fmaf_rn(q.y, p.y, __fmul_rn(q.x, p.x)));
        float d2 = __fsub_rn(__fadd_rn(q.w, p.w), __fmul_rn(2.0f, dot));
        float nd = d2;
        u32 ni = (u32)j;
#pragma unroll
        for (int t = 0; t < c; ++t) {
            bool lt = nd < ko[t];             // strict: equal d2 keeps stream order
            float dmin = lt ? nd : ko[t];
            float dmax = lt ? ko[t] : nd;
            u32 imin = lt ? ni : ki[t];
            u32 imax = lt ? ki[t] : ni;
            ko[t] = dmin; ki[t] = imin;
            nd = dmax;   ni = imax;
        }
        ko[c] = nd; ki[c] = ni;
    }

    // ---- steady scan: cc = 1..7, prune vs wave-shared T and own 16th ----
    for (int cc = 1; cc < 8; ++cc) {
        float T = ko[KNN - 1];
#pragma unroll
        for (int s = 1; s < 64; s <<= 1) T = fminf(T, __shfl_xor(T, s, 64));

#pragma unroll 4
        for (int c = 0; c < 16; ++c) {
            int j = (cc * 16 + c) * 64 + lane;
            float4 p = P[j];
            float dot = __fmaf_rn(q.z, p.z, __fmaf_rn(q.y, p.y, __fmul_rn(q.x, p.x)));
            float d2 = __fsub_rn(__fadd_rn(q.w, p.w), __fmul_rn(2.0f, dot));
            // d2 <= T: boundary ties must be admitted (cross-lane tie-break
            // happens at the tournament); d2 < ko[15]: strict (own-lane equal
            // entries have lower index, rank candidate >= 17 in-lane).
            if (d2 <= T && d2 < ko[KNN - 1]) {
                float nd = d2;
                u32 ni = (u32)j;
#pragma unroll
                for (int t = 0; t < KNN; ++t) {
                    bool lt = nd < ko[t];
                    float dmin = lt ? nd : ko[t];
                    float dmax = lt ? ko[t] : nd;
                    u32 imin = lt ? ni : ki[t];
                    u32 imax = lt ? ki[t] : ni;
                    ko[t] = dmin; ki[t] = imin;
                    nd = dmax;   ni = imax;
                }
            }
        }
    }

    // ---- build exact u64 keys (tie -> lower index) for the merge ----
    u64 kk[KNN];
#pragma unroll
    for (int t = 0; t < KNN; ++t)
        kk[t] = ((u64)f2ord(ko[t]) << 13) | ki[t];   // stays sorted ascending

    // tournament merge: keys are globally unique (idx embedded), winner pops
    // from exactly one lane's list each round.
    u32 myidx = 0;
    float myd2 = 0.0f;
#pragma unroll 1
    for (int r = 0; r < KNN; ++r) {
        u64 m = kk[0];
#pragma unroll
        for (int s = 1; s < 64; s <<= 1) {
            u64 o = shflx64(m, s);
            m = o < m ? o : m;
        }
        if (kk[0] == m) {
#pragma unroll
            for (int t = 0; t < KNN - 1; ++t) kk[t] = kk[t + 1];
            kk[KNN - 1] = ~0ULL;
        }
        if (lane == r) {
            myidx = (u32)(m & (NPTS - 1));
            myd2 = ord2f((u32)(m >> 13));
        }
    }

    if (lane < KNN) {
        // outputs: NN [B,K,N] then distances [B,K,N], both as float32
        size_t o1 = (size_t)(b * KNN + lane) * NPTS + i;
        out[o1] = (float)myidx;
        out[(size_t)NB * KNN * NPTS + o1] = myd2;
    }
}

extern "C" void kernel_launch(void* const* d_in, const int* in_sizes, int n_in,
                              void* d_out, int out_size, void* d_ws, size_t ws_size,
                              hipStream_t stream) {
    const float* pos = (const float*)d_in[0];
    float* out = (float*)d_out;
    float4* pos4 = (float4*)d_ws;   // 4*8192*16 B = 512 KB scratch

    pack_kernel<<<dim3(NB * NPTS / 256), dim3(256), 0, stream>>>(pos, pos4);
    knn_kernel<<<dim3(NB * NPTS / 4), dim3(256), 0, stream>>>(pos4, out);
}

// Round 9
// 340.559 us; speedup vs baseline: 2.5884x; 2.0887x over previous
//
#include <hip/hip_runtime.h>
#include <stdint.h>

#define NPTS 8192
#define NB 4
#define KNN 16
#define BUFCAP 512   // per-wave LDS survivor buffer (u64 keys)
#define TRIG 256     // select when cnt exceeds this (slack 4 steps * 64 lanes = 256)

typedef unsigned long long u64;
typedef unsigned int u32;

// monotone float -> uint32 transform (ascending float order == ascending uint order)
__device__ __forceinline__ u32 f2ord(float f) {
    u32 b = __float_as_uint(f);
    return (b & 0x80000000u) ? ~b : (b | 0x80000000u);
}
__device__ __forceinline__ float ord2f(u32 u) {
    u32 b = (u & 0x80000000u) ? (u & 0x7fffffffu) : ~u;
    return __uint_as_float(b);
}
__device__ __forceinline__ u64 shflx64(u64 v, int m) {
    u32 lo = (u32)v, hi = (u32)(v >> 32);
    lo = __shfl_xor(lo, m, 64);
    hi = __shfl_xor(hi, m, 64);
    return ((u64)hi << 32) | lo;
}
// branchless compare-exchange (ascending) on u64 keys
#define CMPX(A, B) { u64 _a = (A), _b = (B); bool _lt = _b < _a; (A) = _lt ? _b : _a; (B) = _lt ? _a : _b; }

// Pack (x, y, z, ||x||^2) per point. sq via mul-add chain (np.sum(p*p)):
// ((x*x + y*y) + z*z), all _rn (one IEEE rounding per op, no contraction).
__global__ __launch_bounds__(256) void pack_kernel(const float* __restrict__ pos,
                                                   float4* __restrict__ pos4) {
    int t = blockIdx.x * 256 + threadIdx.x;
    int b = t >> 13;
    int j = t & (NPTS - 1);
    const float* p = pos + (size_t)b * 3 * NPTS;
    float x = p[j];
    float y = p[NPTS + j];
    float z = p[2 * NPTS + j];
    float sq = __fadd_rn(__fadd_rn(__fmul_rn(x, x), __fmul_rn(y, y)), __fmul_rn(z, z));
    pos4[t] = make_float4(x, y, z, sq);
}

// One wave per query row. Filter-and-defer: scan keeps NO per-lane top list,
// only a wave-uniform threshold T (d2 of the exact 16th-smallest seen at the
// last selection). Survivors (d2 < T) are appended to a per-wave LDS buffer
// via ballot+prefix; selection (sort-8 + tournament + bitonic merge on exact
// u64 (ord(d2)<<13|idx) keys) runs after warm-up, on buffer pressure, and at
// the end. Strict < prune is exact: later candidates have strictly larger
// indices, so a d2==T candidate ranks >= 17 (tie -> lower index wins).
__global__ __launch_bounds__(256) void knn_kernel(const float4* __restrict__ pos4,
                                                  float* __restrict__ out) {
    __shared__ u64 buf[4][BUFCAP];
    const int lane = threadIdx.x & 63;
    const int wv = threadIdx.x >> 6;
    const int row = blockIdx.x * 4 + wv;          // 0..32767
    const int b = row >> 13;
    const int i = row & (NPTS - 1);

    const float4* __restrict__ P = pos4 + (size_t)b * NPTS;
    const float4 q = P[i];   // wave-uniform broadcast load

    // ---- warm-up: candidates 0..1023, per-lane sorted-16 u64 keys ----
    u64 kk[KNN];
#pragma unroll
    for (int c = 0; c < KNN; ++c) {
        int j = c * 64 + lane;
        float4 p = P[j];
        float dot = __fmaf_rn(q.z, p.z, __fmaf_rn(q.y, p.y, __fmul_rn(q.x, p.x)));
        float d2 = __fsub_rn(__fadd_rn(q.w, p.w), __fmul_rn(2.0f, dot));
        u64 nk = ((u64)f2ord(d2) << 13) | (u32)j;
#pragma unroll
        for (int t = 0; t < c; ++t) {
            u64 lo = kk[t] < nk ? kk[t] : nk;
            nk = kk[t] ^ nk ^ lo;   // the larger one
            kk[t] = lo;
        }
        kk[c] = nk;
    }

    // ---- select 1: tournament over per-lane sorted-16 -> cur (replicated,
    // sorted ascending). Winner value m is uniform, so all lanes record it.
    u64 cur[KNN];
#pragma unroll 1
    for (int r = 0; r < KNN; ++r) {
        u64 m = kk[0];
#pragma unroll
        for (int s = 1; s < 64; s <<= 1) { u64 o = shflx64(m, s); m = o < m ? o : m; }
        if (kk[0] == m) {
#pragma unroll
            for (int t = 0; t < KNN - 1; ++t) kk[t] = kk[t + 1];
            kk[KNN - 1] = ~0ULL;
        }
        cur[r] = m;
    }
    float T = ord2f((u32)(cur[KNN - 1] >> 13));
    int cnt = 0;   // wave-uniform -> SGPR

    // batch selection: merge buf[0..cnt) into cur, tighten T, reset cnt.
    auto do_select = [&]() {
        u64 s8[8];   // cnt <= 512 -> at most 8 entries per lane (round-robin)
#pragma unroll
        for (int r = 0; r < 8; ++r) {
            int bi = r * 64 + lane;
            s8[r] = (bi < cnt) ? buf[wv][bi] : ~0ULL;
        }
        // Batcher odd-even sort-8 (19 comparators), ascending
        CMPX(s8[0], s8[1]) CMPX(s8[2], s8[3]) CMPX(s8[4], s8[5]) CMPX(s8[6], s8[7])
        CMPX(s8[0], s8[2]) CMPX(s8[1], s8[3]) CMPX(s8[4], s8[6]) CMPX(s8[5], s8[7])
        CMPX(s8[1], s8[2]) CMPX(s8[5], s8[6])
        CMPX(s8[0], s8[4]) CMPX(s8[1], s8[5]) CMPX(s8[2], s8[6]) CMPX(s8[3], s8[7])
        CMPX(s8[2], s8[4]) CMPX(s8[3], s8[5])
        CMPX(s8[1], s8[2]) CMPX(s8[3], s8[4]) CMPX(s8[5], s8[6])
        // tournament over depth-8 lists -> nw (replicated, sorted ascending)
        u64 nw[KNN];
#pragma unroll 1
        for (int r = 0; r < KNN; ++r) {
            u64 m = s8[0];
#pragma unroll
            for (int s = 1; s < 64; s <<= 1) { u64 o = shflx64(m, s); m = o < m ? o : m; }
            if (s8[0] == m) {
#pragma unroll
                for (int t = 0; t < 7; ++t) s8[t] = s8[t + 1];
                s8[7] = ~0ULL;
            }
            nw[r] = m;
        }
        // lower-16 of merge(cur, nw): half-cleaner on cur ++ reverse(nw)
#pragma unroll
        for (int t = 0; t < KNN; ++t) {
            u64 o = nw[KNN - 1 - t];
            cur[t] = cur[t] < o ? cur[t] : o;
        }
        // cur is now bitonic; bitonic-clean to ascending (distances 8,4,2,1)
#pragma unroll
        for (int t = 0; t < 8; ++t) CMPX(cur[t], cur[t + 8])
#pragma unroll
        for (int t = 0; t < 16; ++t) if (!(t & 4)) CMPX(cur[t], cur[t + 4])
#pragma unroll
        for (int t = 0; t < 16; ++t) if (!(t & 2)) CMPX(cur[t], cur[t + 2])
#pragma unroll
        for (int t = 0; t < 16; ++t) if (!(t & 1)) CMPX(cur[t], cur[t + 1])
        T = ord2f((u32)(cur[KNN - 1] >> 13));
        cnt = 0;
    };

    // ---- steady scan: candidates 1024..8191, filter + ballot-append ----
#pragma unroll 1
    for (int g = 4; g < 32; ++g) {
#pragma unroll
        for (int c = 0; c < 4; ++c) {
            int j = (g * 4 + c) * 64 + lane;
            float4 p = P[j];
            float dot = __fmaf_rn(q.z, p.z, __fmaf_rn(q.y, p.y, __fmul_rn(q.x, p.x)));
            float d2 = __fsub_rn(__fadd_rn(q.w, p.w), __fmul_rn(2.0f, dot));
            bool pass = d2 < T;
            u64 bal = __ballot(pass);
            if (bal) {
                if (pass) {
                    int pos = cnt + (int)__popcll(bal & ((1ull << lane) - 1ull));
                    buf[wv][pos] = ((u64)f2ord(d2) << 13) | (u32)j;
                }
                cnt += (int)__popcll(bal);
            }
        }
        if (cnt > TRIG) do_select();   // keeps cnt <= BUFCAP always
    }
    if (cnt > 0) do_select();

    // ---- output: cur replicated sorted; lane r emits rank r ----
    u64 mine = ~0ULL;
#pragma unroll
    for (int t = 0; t < KNN; ++t) mine = (lane == t) ? cur[t] : mine;
    if (lane < KNN) {
        size_t o1 = (size_t)(b * KNN + lane) * NPTS + i;
        out[o1] = (float)(u32)(mine & (u64)(NPTS - 1));
        out[(size_t)NB * KNN * NPTS + o1] = ord2f((u32)(mine >> 13));
    }
}

extern "C" void kernel_launch(void* const* d_in, const int* in_sizes, int n_in,
                              void* d_out, int out_size, void* d_ws, size_t ws_size,
                              hipStream_t stream) {
    const float* pos = (const float*)d_in[0];
    float* out = (float*)d_out;
    float4* pos4 = (float4*)d_ws;   // 4*8192*16 B = 512 KB scratch

    pack_kernel<<<dim3(NB * NPTS / 256), dim3(256), 0, stream>>>(pos, pos4);
    knn_kernel<<<dim3(NB * NPTS / 4), dim3(256), 0, stream>>>(pos4, out);
}

// Round 10
// 277.216 us; speedup vs baseline: 3.1798x; 1.2285x over previous
//
#include <hip/hip_runtime.h>
#include <stdint.h>

#define NPTS 8192
#define NB 4
#define KNN 16
#define BUFCAP 512   // per-wave LDS survivor buffer (u64 keys)
#define TRIG 256     // select when cnt >= TRIG (max +256 per group keeps cnt <= 512)

typedef unsigned long long u64;
typedef unsigned int u32;

// monotone float -> uint32 transform (ascending float order == ascending uint order)
__device__ __forceinline__ u32 f2ord(float f) {
    u32 b = __float_as_uint(f);
    return (b & 0x80000000u) ? ~b : (b | 0x80000000u);
}
__device__ __forceinline__ float ord2f(u32 u) {
    u32 b = (u & 0x80000000u) ? (u & 0x7fffffffu) : ~u;
    return __uint_as_float(b);
}
__device__ __forceinline__ u64 shflx64(u64 v, int m) {
    u32 lo = (u32)v, hi = (u32)(v >> 32);
    lo = __shfl_xor(lo, m, 64);
    hi = __shfl_xor(hi, m, 64);
    return ((u64)hi << 32) | lo;
}
// branchless compare-exchange (ascending) on u64 keys
#define CMPX(A, B) { u64 _a = (A), _b = (B); bool _lt = _b < _a; (A) = _lt ? _b : _a; (B) = _lt ? _a : _b; }

// Pack (x, y, z, ||x||^2) per point. sq via mul-add chain (np.sum(p*p)):
// ((x*x + y*y) + z*z), all _rn (one IEEE rounding per op, no contraction).
__global__ __launch_bounds__(256) void pack_kernel(const float* __restrict__ pos,
                                                   float4* __restrict__ pos4) {
    int t = blockIdx.x * 256 + threadIdx.x;
    int b = t >> 13;
    int j = t & (NPTS - 1);
    const float* p = pos + (size_t)b * 3 * NPTS;
    float x = p[j];
    float y = p[NPTS + j];
    float z = p[2 * NPTS + j];
    float sq = __fadd_rn(__fadd_rn(__fmul_rn(x, x), __fmul_rn(y, y)), __fmul_rn(z, z));
    pos4[t] = make_float4(x, y, z, sq);
}

// One wave per query row. No warm-up: T starts at +inf so the first 256
// candidates self-append; thereafter the trigger path tightens T. Mid-scan
// tightening is CHEAP: T' = d2 of the 16th-smallest per-lane-min (found by
// 32-step ballot bisection on the 32-bit ord). Validity: 16 lanes have >= 1
// entry <= T' => >= 16 buffer entries <= T'; any pruned candidate (d2 >= T',
// strictly larger index than all buffer entries) has >= 16 strictly smaller
// u64 keys => exact. Buffer is compacted to entries <= T'. If > 256 would be
// retained (adversarial data), fall back to the exact select. One exact
// select (sort-8 + 16-round tournament on unique u64 keys) at the end.
__global__ __launch_bounds__(256) void knn_kernel(const float4* __restrict__ pos4,
                                                  float* __restrict__ out) {
    __shared__ u64 buf[4][BUFCAP];
    const int lane = threadIdx.x & 63;
    const int wv = threadIdx.x >> 6;
    const int row = blockIdx.x * 4 + wv;          // 0..32767
    const int b = row >> 13;
    const int i = row & (NPTS - 1);

    const float4* __restrict__ P = pos4 + (size_t)b * NPTS;
    const float4 q = P[i];   // wave-uniform broadcast load

    float T = __uint_as_float(0x7f800000u);   // +inf
    int cnt = 0;                              // wave-uniform -> SGPR
    u64 myk = ~0ULL;                          // lane r (<16) ends with rank r

    // exact select over buf[0..cnt): sorted-8/lane + 16-round tournament.
    // Re-appends the 16 winners (lane 0) so it is safe mid-scan too.
    auto exact_select = [&]() {
        u64 s8[8];
#pragma unroll
        for (int r = 0; r < 8; ++r) {
            int bi = r * 64 + lane;
            s8[r] = (bi < cnt) ? buf[wv][bi] : ~0ULL;
        }
        // Batcher odd-even sort-8 (19 comparators), ascending
        CMPX(s8[0], s8[1]) CMPX(s8[2], s8[3]) CMPX(s8[4], s8[5]) CMPX(s8[6], s8[7])
        CMPX(s8[0], s8[2]) CMPX(s8[1], s8[3]) CMPX(s8[4], s8[6]) CMPX(s8[5], s8[7])
        CMPX(s8[1], s8[2]) CMPX(s8[5], s8[6])
        CMPX(s8[0], s8[4]) CMPX(s8[1], s8[5]) CMPX(s8[2], s8[6]) CMPX(s8[3], s8[7])
        CMPX(s8[2], s8[4]) CMPX(s8[3], s8[5])
        CMPX(s8[1], s8[2]) CMPX(s8[3], s8[4]) CMPX(s8[5], s8[6])
        u64 lastm = 0;
#pragma unroll 1
        for (int r = 0; r < KNN; ++r) {
            u64 m = s8[0];
#pragma unroll
            for (int s = 1; s < 64; s <<= 1) { u64 o = shflx64(m, s); m = o < m ? o : m; }
            if (s8[0] == m) {
#pragma unroll
                for (int t = 0; t < 7; ++t) s8[t] = s8[t + 1];
                s8[7] = ~0ULL;
            }
            if (lane == r) myk = m;
            if (lane == 0) buf[wv][r] = m;
            lastm = m;
        }
        cnt = KNN;
        T = ord2f((u32)(lastm >> 13));
    };

    // ---- scan: 32 groups x 4 steps, filter + ballot-append ----
#pragma unroll 1
    for (int g = 0; g < 32; ++g) {
#pragma unroll
        for (int c = 0; c < 4; ++c) {
            int j = (g * 4 + c) * 64 + lane;
            float4 p = P[j];
            // exact reference arithmetic (BLAS-fma dot, _rn combine)
            float dot = __fmaf_rn(q.z, p.z, __fmaf_rn(q.y, p.y, __fmul_rn(q.x, p.x)));
            float d2 = __fsub_rn(__fadd_rn(q.w, p.w), __fmul_rn(2.0f, dot));
            bool pass = d2 < T;
            u64 bal = __ballot(pass);
            if (bal) {
                if (pass) {
                    int pos = cnt + (int)__popcll(bal & ((1ull << lane) - 1ull));
                    buf[wv][pos] = ((u64)f2ord(d2) << 13) | (u32)j;
                }
                cnt += (int)__popcll(bal);
            }
        }
        if (cnt >= TRIG) {
            // cheap tighten: 16th-smallest lane-min via ballot bisection
            u64 s8[8];
#pragma unroll
            for (int r = 0; r < 8; ++r) {
                int bi = r * 64 + lane;
                s8[r] = (bi < cnt) ? buf[wv][bi] : ~0ULL;
            }
            u64 lm = s8[0];
            lm = s8[1] < lm ? s8[1] : lm;
            lm = s8[2] < lm ? s8[2] : lm;
            lm = s8[3] < lm ? s8[3] : lm;      // slots 0..255 all real (cnt>=256)
            u32 x = (u32)(lm >> 13);           // ord(d2) of my min
            u32 lo = 0u, hi = 0xFFFFFFFFu;
#pragma unroll 1
            for (int it = 0; it < 32; ++it) {
                u32 mid = lo + ((hi - lo) >> 1);
                int cle = (int)__popcll(__ballot(x <= mid));
                if (cle >= 16) hi = mid; else lo = mid + 1;
            }
            // hi = ord of 16th-smallest lane-min; >=16 entries have ord <= hi
            int rc = 0;
#pragma unroll
            for (int r = 0; r < 8; ++r)
                rc += (int)__popcll(__ballot((u32)(s8[r] >> 13) <= hi));
            if (rc <= TRIG) {
                int nc = 0;
#pragma unroll
                for (int r = 0; r < 8; ++r) {
                    bool keep = (u32)(s8[r] >> 13) <= hi;
                    u64 balr = __ballot(keep);
                    if (keep)
                        buf[wv][nc + (int)__popcll(balr & ((1ull << lane) - 1ull))] = s8[r];
                    nc += (int)__popcll(balr);
                }
                cnt = nc;
                T = ord2f(hi);
            } else {
                exact_select();   // adversarial-data fallback, exact
            }
        }
    }

    // ---- final exact selection + output ----
    exact_select();
    if (lane < KNN) {
        size_t o1 = (size_t)(b * KNN + lane) * NPTS + i;
        out[o1] = (float)(u32)(myk & (u64)(NPTS - 1));
        out[(size_t)NB * KNN * NPTS + o1] = ord2f((u32)(myk >> 13));
    }
}

extern "C" void kernel_launch(void* const* d_in, const int* in_sizes, int n_in,
                              void* d_out, int out_size, void* d_ws, size_t ws_size,
                              hipStream_t stream) {
    const float* pos = (const float*)d_in[0];
    float* out = (float*)d_out;
    float4* pos4 = (float4*)d_ws;   // 4*8192*16 B = 512 KB scratch

    pack_kernel<<<dim3(NB * NPTS / 256), dim3(256), 0, stream>>>(pos, pos4);
    knn_kernel<<<dim3(NB * NPTS / 4), dim3(256), 0, stream>>>(pos4, out);
}

// Round 11
// 219.784 us; speedup vs baseline: 4.0108x; 1.2613x over previous
//
#include <hip/hip_runtime.h>
#include <stdint.h>

#define NPTS 8192
#define NPAIR 4096
#define NB 4
#define KNN 16
#define BUFCAP 768   // per-wave LDS survivor buffer (u64 keys)
#define TRIG 256     // tighten when cnt >= TRIG; max +512/group keeps cnt <= 768
#define NSLOT 12     // BUFCAP / 64

typedef unsigned long long u64;
typedef unsigned int u32;

// monotone float -> uint32 transform (ascending float order == ascending uint order)
__device__ __forceinline__ u32 f2ord(float f) {
    u32 b = __float_as_uint(f);
    return (b & 0x80000000u) ? ~b : (b | 0x80000000u);
}
__device__ __forceinline__ float ord2f(u32 u) {
    u32 b = (u & 0x80000000u) ? (u & 0x7fffffffu) : ~u;
    return __uint_as_float(b);
}
__device__ __forceinline__ u64 shflx64(u64 v, int m) {
    u32 lo = (u32)v, hi = (u32)(v >> 32);
    lo = __shfl_xor(lo, m, 64);
    hi = __shfl_xor(hi, m, 64);
    return ((u64)hi << 32) | lo;
}

// Pair-packed SoA: for batch b, pair m (points 2m, 2m+1):
//   pos8[(b*NPAIR+m)*2+0] = {x0, x1, y0, y1}
//   pos8[(b*NPAIR+m)*2+1] = {z0, z1, sq0, sq1}
// sq via mul-add chain (np.sum(p*p)): ((x*x + y*y) + z*z), all _rn.
__global__ __launch_bounds__(256) void pack_kernel(const float* __restrict__ pos,
                                                   float4* __restrict__ pos8) {
    int t = blockIdx.x * 256 + threadIdx.x;   // 0..16383
    int b = t >> 12;
    int m = t & (NPAIR - 1);
    const float* p = pos + (size_t)b * 3 * NPTS;
    float2 x = *(const float2*)&p[2 * m];
    float2 y = *(const float2*)&p[NPTS + 2 * m];
    float2 z = *(const float2*)&p[2 * NPTS + 2 * m];
    float s0 = __fadd_rn(__fadd_rn(__fmul_rn(x.x, x.x), __fmul_rn(y.x, y.x)), __fmul_rn(z.x, z.x));
    float s1 = __fadd_rn(__fadd_rn(__fmul_rn(x.y, x.y), __fmul_rn(y.y, y.y)), __fmul_rn(z.y, z.y));
    pos8[2 * t]     = make_float4(x.x, x.y, y.x, y.y);
    pos8[2 * t + 1] = make_float4(z.x, z.y, s0, s1);
}

// One wave per query row. Bootstrap: first 512 candidates appended at fixed
// positions (no filter), then tighten. Steady: filter d2 < T, ballot-append;
// tighten (16th-smallest lane-min via 32-step ballot bisection + compaction)
// when cnt >= TRIG. Exactness: >=16 buffer entries have d2 <= T', and all
// buffer entries have smaller indices than future candidates, so any pruned
// candidate (d2 >= T') has >=16 strictly smaller (d2, idx) keys. Discarded
// entries (d2 > T') likewise have >=16 smaller keys. Final: if cnt <= 64,
// cross-lane bitonic sort-64 (keys unique -> exact total order); else exact
// 16-round extract-min tournament (also the adversarial tighten fallback).
__global__ __launch_bounds__(256) void knn_kernel(const float4* __restrict__ pos8,
                                                  float* __restrict__ out) {
    __shared__ u64 buf[4][BUFCAP];
    const int lane = threadIdx.x & 63;
    const int wv = threadIdx.x >> 6;
    const int row = blockIdx.x * 4 + wv;          // 0..32767
    const int b = row >> 13;
    const int i = row & (NPTS - 1);

    const float4* __restrict__ P8 = pos8 + (size_t)b * NPAIR * 2;

    // query fetch from packed layout
    float qx, qy, qz, qw;
    {
        int m = i >> 1, h = i & 1;
        float4 a = P8[2 * m], c = P8[2 * m + 1];
        qx = h ? a.y : a.x;
        qy = h ? a.w : a.z;
        qz = h ? c.y : c.x;
        qw = h ? c.w : c.z;
    }

    float T;
    int cnt;                      // wave-uniform -> SGPR
    u64 myk = ~0ULL;              // lane r (<16) ends with rank-r key

    // exact 16-round extract-min over buf[0..cnt) (cnt <= BUFCAP).
    // Leaves winners in buf[0..15], cnt=16, T = d2 of 16th. Keys unique.
    auto extract16 = [&](bool store) {
        u64 s12[NSLOT];
#pragma unroll
        for (int r = 0; r < NSLOT; ++r) {
            int bi = r * 64 + lane;
            s12[r] = (bi < cnt) ? buf[wv][bi] : ~0ULL;
        }
        u64 mm = 0;
#pragma unroll 1
        for (int r = 0; r < KNN; ++r) {
            u64 lm = s12[0];
#pragma unroll
            for (int t = 1; t < NSLOT; ++t) lm = s12[t] < lm ? s12[t] : lm;
            mm = lm;
#pragma unroll
            for (int s = 1; s < 64; s <<= 1) { u64 o = shflx64(mm, s); mm = o < mm ? o : mm; }
#pragma unroll
            for (int t = 0; t < NSLOT; ++t) s12[t] = (s12[t] == mm) ? ~0ULL : s12[t];
            if (store && lane == r) myk = mm;
            if (lane == 0) buf[wv][r] = mm;
        }
        cnt = KNN;
        T = ord2f((u32)(mm >> 13));
    };

    // tighten: T' = d2 of 16th-smallest per-lane-min (ballot bisection on ord),
    // compact buffer to entries <= T'. Falls back to extract16 if > TRIG retained.
    auto tighten = [&]() {
        u64 s12[NSLOT];
        u64 lm = ~0ULL;
#pragma unroll
        for (int r = 0; r < NSLOT; ++r) {
            int bi = r * 64 + lane;
            s12[r] = (bi < cnt) ? buf[wv][bi] : ~0ULL;
            lm = s12[r] < lm ? s12[r] : lm;
        }
        u32 x = (u32)(lm >> 13);   // cnt >= 64 -> every lane's slot 0 is real
        u32 lo = 0u, hi = 0xFFFFFFFFu;
#pragma unroll 1
        for (int it = 0; it < 32; ++it) {
            u32 mid = lo + ((hi - lo) >> 1);
            int cle = (int)__popcll(__ballot(x <= mid));
            if (cle >= KNN) hi = mid; else lo = mid + 1;
        }
        // hi = ord of 16th-smallest lane-min => >=16 entries with ord <= hi
        int rc = 0;
#pragma unroll
        for (int r = 0; r < NSLOT; ++r)
            rc += (int)__popcll(__ballot(s12[r] != ~0ULL && (u32)(s12[r] >> 13) <= hi));
        if (rc <= TRIG) {
            int nc = 0;
#pragma unroll
            for (int r = 0; r < NSLOT; ++r) {
                bool keep = s12[r] != ~0ULL && (u32)(s12[r] >> 13) <= hi;
                u64 bal = __ballot(keep);
                if (keep)
                    buf[wv][nc + (int)__popcll(bal & ((1ull << lane) - 1ull))] = s12[r];
                nc += (int)__popcll(bal);
            }
            cnt = nc;
            T = ord2f(hi);
        } else {
            extract16(false);   // adversarial-data fallback, exact
        }
    };

    // ---- bootstrap: pairs 0..255 (candidates 0..511), unconditional append ----
#pragma unroll
    for (int s = 0; s < 4; ++s) {
        int m = s * 64 + lane;
        float4 a = P8[2 * m], c = P8[2 * m + 1];
        // exact reference arithmetic (BLAS-fma dot, _rn combine)
        float dot0 = __fmaf_rn(qz, c.x, __fmaf_rn(qy, a.z, __fmul_rn(qx, a.x)));
        float dot1 = __fmaf_rn(qz, c.y, __fmaf_rn(qy, a.w, __fmul_rn(qx, a.y)));
        float d0 = __fsub_rn(__fadd_rn(qw, c.z), __fmul_rn(2.0f, dot0));
        float d1 = __fsub_rn(__fadd_rn(qw, c.w), __fmul_rn(2.0f, dot1));
        buf[wv][(2 * s) * 64 + lane]     = ((u64)f2ord(d0) << 13) | (u32)(2 * m);
        buf[wv][(2 * s + 1) * 64 + lane] = ((u64)f2ord(d1) << 13) | (u32)(2 * m + 1);
    }
    cnt = 512;
    tighten();

    // ---- steady scan: 15 groups x 4 steps x 2 candidates/lane ----
#pragma unroll 1
    for (int g = 1; g < 16; ++g) {
        int base = g * 256;
        float d2a[4], d2b[4];
#pragma unroll
        for (int s = 0; s < 4; ++s) {
            int m = base + s * 64 + lane;
            float4 a = P8[2 * m], c = P8[2 * m + 1];
            float dot0 = __fmaf_rn(qz, c.x, __fmaf_rn(qy, a.z, __fmul_rn(qx, a.x)));
            float dot1 = __fmaf_rn(qz, c.y, __fmaf_rn(qy, a.w, __fmul_rn(qx, a.y)));
            d2a[s] = __fsub_rn(__fadd_rn(qw, c.z), __fmul_rn(2.0f, dot0));
            d2b[s] = __fsub_rn(__fadd_rn(qw, c.w), __fmul_rn(2.0f, dot1));
        }
#pragma unroll
        for (int s = 0; s < 4; ++s) {
            int j0 = 2 * (base + s * 64 + lane);
            bool pa = d2a[s] < T;
            u64 bal = __ballot(pa);
            if (bal) {
                if (pa)
                    buf[wv][cnt + (int)__popcll(bal & ((1ull << lane) - 1ull))] =
                        ((u64)f2ord(d2a[s]) << 13) | (u32)j0;
                cnt += (int)__popcll(bal);
            }
            bool pb = d2b[s] < T;
            bal = __ballot(pb);
            if (bal) {
                if (pb)
                    buf[wv][cnt + (int)__popcll(bal & ((1ull << lane) - 1ull))] =
                        ((u64)f2ord(d2b[s]) << 13) | (u32)(j0 + 1);
                cnt += (int)__popcll(bal);
            }
        }
        if (cnt >= TRIG) tighten();
    }

    // ---- final selection ----
    if (cnt <= 64) {
        // cross-lane bitonic sort-64 (unique keys; ~0 padding sorts high)
        u64 v = (lane < cnt) ? buf[wv][lane] : ~0ULL;
#pragma unroll
        for (int k = 2; k <= 64; k <<= 1) {
#pragma unroll
            for (int jj = k >> 1; jj >= 1; jj >>= 1) {
                u64 o = shflx64(v, jj);
                bool takeMin = ((lane & k) == 0) == ((lane & jj) == 0);
                bool vlt = v < o;
                v = (takeMin == vlt) ? v : o;
            }
        }
        myk = v;   // lane r holds rank r
    } else {
        extract16(true);
    }

    if (lane < KNN) {
        // outputs: NN [B,K,N] then distances [B,K,N], both as float32
        size_t o1 = (size_t)(b * KNN + lane) * NPTS + i;
        out[o1] = (float)(u32)(myk & (u64)(NPTS - 1));
        out[(size_t)NB * KNN * NPTS + o1] = ord2f((u32)(myk >> 13));
    }
}

extern "C" void kernel_launch(void* const* d_in, const int* in_sizes, int n_in,
                              void* d_out, int out_size, void* d_ws, size_t ws_size,
                              hipStream_t stream) {
    const float* pos = (const float*)d_in[0];
    float* out = (float*)d_out;
    float4* pos8 = (float4*)d_ws;   // 4*4096*2*16 B = 512 KB scratch

    pack_kernel<<<dim3(NB * NPAIR / 256), dim3(256), 0, stream>>>(pos, pos8);
    knn_kernel<<<dim3(NB * NPTS / 4), dim3(256), 0, stream>>>(pos8, out);
}